// Round 17
// baseline (6238.359 us; speedup 1.0000x reference)
//
#include <hip/hip_runtime.h>
#include <cstdint>
#include <cstddef>

#define HID 64

typedef short bf16x8 __attribute__((ext_vector_type(8)));
typedef float f32x4 __attribute__((ext_vector_type(4)));
typedef float f32x2 __attribute__((ext_vector_type(2)));
typedef unsigned u32x4 __attribute__((ext_vector_type(4)));

__device__ __forceinline__ f32x2 c2(float v) { f32x2 r = {v, v}; return r; }

// Packed exact-erf GELU (A&S 7.1.26, max |erf err| ~1.5e-7) on two elements.
__device__ __forceinline__ f32x2 fast_gelu2(f32x2 z) {
    const f32x2 u = z * 0.70710678118654752f;
    const f32x2 a = __builtin_elementwise_abs(u);
    const f32x2 d = __builtin_elementwise_fma(c2(0.3275911f), a, c2(1.0f));
    f32x2 t;
    t.x = __builtin_amdgcn_rcpf(d.x);
    t.y = __builtin_amdgcn_rcpf(d.y);
    const f32x2 s = u * 1.20112240878645f;      // sqrt(log2 e)
    f32x2 e;
    e.x = __builtin_amdgcn_exp2f(-(s.x * s.x)); // exp(-u^2)
    e.y = __builtin_amdgcn_exp2f(-(s.y * s.y));
    f32x2 p = c2(1.061405429f);
    p = __builtin_elementwise_fma(p, t, c2(-1.453152027f));
    p = __builtin_elementwise_fma(p, t, c2( 1.421413741f));
    p = __builtin_elementwise_fma(p, t, c2(-0.284496736f));
    p = __builtin_elementwise_fma(p, t, c2( 0.254829592f));
    p = p * t;
    f32x2 er = __builtin_elementwise_fma(-p, e, c2(1.0f));
    er = __builtin_elementwise_copysign(er, u);
    const f32x2 zh = z * 0.5f;
    return __builtin_elementwise_fma(zh, er, zh);
}

__device__ __forceinline__ ushort bf16_hi(float f) {
    return (ushort)(__float_as_uint(f) >> 16);
}
__device__ __forceinline__ float bf16_f(ushort u) {
    return __uint_as_float(((unsigned)u) << 16);
}

// Pack top halves of two f32 bit-patterns into one u32: {lo16=a>>16, hi16=b>>16}.
#define PKHI(b_, a_) __builtin_amdgcn_perm((b_), (a_), 0x07060302u)

__device__ __forceinline__ bf16x8 mk8(unsigned a, unsigned b, unsigned c, unsigned d) {
    union { u32x4 u; bf16x8 v; } w;
    w.u = (u32x4){a, b, c, d};
    return w.v;
}

// bf16-truncation of both elements (bitmask), packed.
__device__ __forceinline__ f32x2 TR2(f32x2 v) {
    f32x2 r;
    r.x = __uint_as_float(__float_as_uint(v.x) & 0xffff0000u);
    r.y = __uint_as_float(__float_as_uint(v.y) & 0xffff0000u);
    return r;
}

#define MF(A_, B_, C_) __builtin_amdgcn_mfma_f32_16x16x32_bf16((A_), (B_), (C_), 0, 0, 0)

// Load W^T A-fragment for c-tile t, K-half hf, under the CUSTOM slot->k map
// k(q,e,hf) = 32*hf + 16*(e>>2) + 4q + (e&3)   (bijection per MFMA call).
// With this map, a lane's step-t D elements ARE its step-t+1 B-fragment --
// no cross-lane exchange, no LDS, no barriers. (Validated: r16 passed.)
#define LDW(VH, VL, t, hf) { \
    _Pragma("unroll") \
    for (int e = 0; e < 8; ++e) { \
        const int k = 32 * (hf) + 16 * (e >> 2) + 4 * q + (e & 3); \
        const float wf = W_s[k * HID + 16 * (t) + rr]; \
        const ushort hb = bf16_hi(wf); \
        VH[e] = (short)hb; \
        VL[e] = (short)bf16_hi(wf - bf16_f(hb)); \
    } }

// One fully in-register step, LATENCY-RESTRUCTURED: 12 independent 2-deep
// MFMA chains (hh with bias C-in, hl, lh per tile), issued 12-then-12 so the
// matrix pipe always has independent work; combine with packed adds; 8
// independent GELU2 streams; repack into next B-frags.
#define STEP(XB) { \
    const f32x4 xb4 = {(XB), (XB), (XB), (XB)}; \
    const f32x4 zz = {0.f, 0.f, 0.f, 0.f}; \
    f32x4 p0 = __builtin_elementwise_fma(xb4, wn0, cv0); \
    f32x4 p1 = __builtin_elementwise_fma(xb4, wn1, cv1); \
    f32x4 p2 = __builtin_elementwise_fma(xb4, wn2, cv2); \
    f32x4 p3 = __builtin_elementwise_fma(xb4, wn3, cv3); \
    /* first K-half: 12 independent MFMAs */ \
    p0 = MF(WH00, BH0, p0);  p1 = MF(WH10, BH0, p1); \
    p2 = MF(WH20, BH0, p2);  p3 = MF(WH30, BH0, p3); \
    f32x4 u0 = MF(WH00, BL0, zz), u1 = MF(WH10, BL0, zz); \
    f32x4 u2 = MF(WH20, BL0, zz), u3 = MF(WH30, BL0, zz); \
    f32x4 v0 = MF(WL00, BH0, zz), v1 = MF(WL10, BH0, zz); \
    f32x4 v2 = MF(WL20, BH0, zz), v3 = MF(WL30, BH0, zz); \
    /* second K-half: each depends only on its own first-half MFMA */ \
    p0 = MF(WH01, BH1, p0);  p1 = MF(WH11, BH1, p1); \
    p2 = MF(WH21, BH1, p2);  p3 = MF(WH31, BH1, p3); \
    u0 = MF(WH01, BL1, u0);  u1 = MF(WH11, BL1, u1); \
    u2 = MF(WH21, BL1, u2);  u3 = MF(WH31, BL1, u3); \
    v0 = MF(WL01, BH1, v0);  v1 = MF(WL11, BH1, v1); \
    v2 = MF(WL21, BH1, v2);  v3 = MF(WL31, BH1, v3); \
    const f32x4 zt0 = (p0 + u0) + v0; \
    const f32x4 zt1 = (p1 + u1) + v1; \
    const f32x4 zt2 = (p2 + u2) + v2; \
    const f32x4 zt3 = (p3 + u3) + v3; \
    f32x2 z; \
    z.x = zt0[0]; z.y = zt0[1]; const f32x2 g0a = fast_gelu2(z); \
    z.x = zt0[2]; z.y = zt0[3]; const f32x2 g0b = fast_gelu2(z); \
    z.x = zt1[0]; z.y = zt1[1]; const f32x2 g1a = fast_gelu2(z); \
    z.x = zt1[2]; z.y = zt1[3]; const f32x2 g1b = fast_gelu2(z); \
    z.x = zt2[0]; z.y = zt2[1]; const f32x2 g2a = fast_gelu2(z); \
    z.x = zt2[2]; z.y = zt2[3]; const f32x2 g2b = fast_gelu2(z); \
    z.x = zt3[0]; z.y = zt3[1]; const f32x2 g3a = fast_gelu2(z); \
    z.x = zt3[2]; z.y = zt3[3]; const f32x2 g3b = fast_gelu2(z); \
    const unsigned h0a = PKHI(__float_as_uint(g0a.y), __float_as_uint(g0a.x)); \
    const unsigned h0b = PKHI(__float_as_uint(g0b.y), __float_as_uint(g0b.x)); \
    const unsigned h1a = PKHI(__float_as_uint(g1a.y), __float_as_uint(g1a.x)); \
    const unsigned h1b = PKHI(__float_as_uint(g1b.y), __float_as_uint(g1b.x)); \
    const unsigned h2a = PKHI(__float_as_uint(g2a.y), __float_as_uint(g2a.x)); \
    const unsigned h2b = PKHI(__float_as_uint(g2b.y), __float_as_uint(g2b.x)); \
    const unsigned h3a = PKHI(__float_as_uint(g3a.y), __float_as_uint(g3a.x)); \
    const unsigned h3b = PKHI(__float_as_uint(g3b.y), __float_as_uint(g3b.x)); \
    const f32x2 l0a = g0a - TR2(g0a); const f32x2 l0b = g0b - TR2(g0b); \
    const f32x2 l1a = g1a - TR2(g1a); const f32x2 l1b = g1b - TR2(g1b); \
    const f32x2 l2a = g2a - TR2(g2a); const f32x2 l2b = g2b - TR2(g2b); \
    const f32x2 l3a = g3a - TR2(g3a); const f32x2 l3b = g3b - TR2(g3b); \
    BH0 = mk8(h0a, h0b, h1a, h1b); \
    BH1 = mk8(h2a, h2b, h3a, h3b); \
    BL0 = mk8(PKHI(__float_as_uint(l0a.y), __float_as_uint(l0a.x)), \
              PKHI(__float_as_uint(l0b.y), __float_as_uint(l0b.x)), \
              PKHI(__float_as_uint(l1a.y), __float_as_uint(l1a.x)), \
              PKHI(__float_as_uint(l1b.y), __float_as_uint(l1b.x))); \
    BL1 = mk8(PKHI(__float_as_uint(l2a.y), __float_as_uint(l2a.x)), \
              PKHI(__float_as_uint(l2b.y), __float_as_uint(l2b.x)), \
              PKHI(__float_as_uint(l3a.y), __float_as_uint(l3a.x)), \
              PKHI(__float_as_uint(l3b.y), __float_as_uint(l3b.x))); }

__global__ __launch_bounds__(64, 1)
void ssm_kernel(const float* __restrict__ x,
                const float* __restrict__ W_in,
                const float* __restrict__ b_in,
                const float* __restrict__ W_s,
                const float* __restrict__ b_s,
                const float* __restrict__ W_out,
                const float* __restrict__ b_out,
                float* __restrict__ out,
                int B, int T) {
    const int lane = threadIdx.x & 63;
    const int q    = lane >> 4;       // k-slot group / D row-quad group
    const int rr   = lane & 15;       // batch row (A's c-row AND D's r-col)
    const int bA   = blockIdx.x * 16;
    if (bA >= B) return;

    // Static W^T fragments (hi+lo split), custom k-map. 128 regs (unified file).
    bf16x8 WH00, WH01, WH10, WH11, WH20, WH21, WH30, WH31;
    bf16x8 WL00, WL01, WL10, WL11, WL20, WL21, WL30, WL31;
    LDW(WH00, WL00, 0, 0) LDW(WH01, WL01, 0, 1)
    LDW(WH10, WL10, 1, 0) LDW(WH11, WL11, 1, 1)
    LDW(WH20, WL20, 2, 0) LDW(WH21, WL21, 2, 1)
    LDW(WH30, WL30, 3, 0) LDW(WH31, WL31, 3, 1)
    asm volatile("" : "+v"(WH00), "+v"(WH01), "+v"(WH10), "+v"(WH11),
                      "+v"(WH20), "+v"(WH21), "+v"(WH30), "+v"(WH31));
    asm volatile("" : "+v"(WL00), "+v"(WL01), "+v"(WL10), "+v"(WL11),
                      "+v"(WL20), "+v"(WL21), "+v"(WL30), "+v"(WL31));

    // Per-tile input-projection constants: el e of tile t is c = 16t + 4q + e.
    f32x4 wn0, wn1, wn2, wn3, cv0, cv1, cv2, cv3;
#pragma unroll
    for (int e = 0; e < 4; ++e) {
        wn0[e] = W_in[ 0 + 4 * q + e];  cv0[e] = b_in[ 0 + 4 * q + e] + b_s[ 0 + 4 * q + e];
        wn1[e] = W_in[16 + 4 * q + e];  cv1[e] = b_in[16 + 4 * q + e] + b_s[16 + 4 * q + e];
        wn2[e] = W_in[32 + 4 * q + e];  cv2[e] = b_in[32 + 4 * q + e] + b_s[32 + 4 * q + e];
        wn3[e] = W_in[48 + 4 * q + e];  cv3[e] = b_in[48 + 4 * q + e] + b_s[48 + 4 * q + e];
    }

    // h state (B-fragments), fully in registers. h0 = 0.
    bf16x8 BH0 = mk8(0, 0, 0, 0), BH1 = mk8(0, 0, 0, 0);
    bf16x8 BL0 = mk8(0, 0, 0, 0), BL1 = mk8(0, 0, 0, 0);

    // This lane's x row (4 steps per f32x4 load; row base is 16B-aligned).
    const float* const xp = x + (size_t)(bA + rr) * (size_t)T;
    const int n4 = T >> 2;
    f32x4 xq = *reinterpret_cast<const f32x4*>(xp);

#pragma unroll 1
    for (int tc = 0; tc < n4; ++tc) {
        const int nx = (tc + 1 < n4) ? (tc + 1) : tc;   // clamped prefetch
        const f32x4 xn = *reinterpret_cast<const f32x4*>(xp + 4 * nx);
        STEP(xq[0])
        STEP(xq[1])
        STEP(xq[2])
        STEP(xq[3])
        xq = xn;
    }

    // Epilogue: lane holds h[c = 16t+4q+e][rr] as (BH,BL) el (t&1)*4+e of
    // half t>>1. out[b] = h . W_out + b_out, reduced over the 4 q-lanes.
    float s = 0.f;
#pragma unroll
    for (int t = 0; t < 4; ++t) {
        const bf16x8 bh = (t < 2) ? BH0 : BH1;
        const bf16x8 bl = (t < 2) ? BL0 : BL1;
#pragma unroll
        for (int e = 0; e < 4; ++e) {
            const int i = (t & 1) * 4 + e;
            const float hv = bf16_f((ushort)bh[i]) + bf16_f((ushort)bl[i]);
            s = __builtin_fmaf(hv, W_out[16 * t + 4 * q + e], s);
        }
    }
    s += __shfl_xor(s, 16, 64);
    s += __shfl_xor(s, 32, 64);
    if (lane < 16) out[bA + rr] = s + b_out[0];
}

extern "C" void kernel_launch(void* const* d_in, const int* in_sizes, int n_in,
                              void* d_out, int out_size, void* d_ws, size_t ws_size,
                              hipStream_t stream) {
    const float* x     = (const float*)d_in[0];
    const float* W_in  = (const float*)d_in[1];
    const float* b_in  = (const float*)d_in[2];
    const float* W_s   = (const float*)d_in[3];
    const float* b_s   = (const float*)d_in[4];
    const float* W_out = (const float*)d_in[5];
    const float* b_out = (const float*)d_in[6];
    float* out = (float*)d_out;

    const int B = out_size;                 // [B,1] output
    const int T = in_sizes[0] / B;          // x is [B,T,1]

    const int blocks = B / 16;              // 256 for B=4096
    ssm_kernel<<<blocks, 64, 0, stream>>>(
        x, W_in, b_in, W_s, b_s, W_out, b_out, out, B, T);
}

// Round 18
// 2564.952 us; speedup vs baseline: 2.4322x; 2.4322x over previous
//
#include <hip/hip_runtime.h>
#include <cstdint>
#include <cstddef>

#define HID 64
#define RPG 16          // rows per block = MFMA N-tile (swapped form)
#define ROWU 144        // ushorts per h row stripe (288B): [hi 8x16B][lo 8x16B][pad 32B]
#define XSTR 68         // floats per x row: 272 B

typedef short bf16x8 __attribute__((ext_vector_type(8)));
typedef float f32x4 __attribute__((ext_vector_type(4)));
typedef float f32x2 __attribute__((ext_vector_type(2)));

__device__ __forceinline__ f32x2 c2(float v) { f32x2 r = {v, v}; return r; }

// Packed exact-erf GELU (A&S 7.1.26, max |erf err| ~1.5e-7) on two elements.
__device__ __forceinline__ f32x2 fast_gelu2(f32x2 z) {
    const f32x2 u = z * 0.70710678118654752f;
    const f32x2 a = __builtin_elementwise_abs(u);
    const f32x2 d = __builtin_elementwise_fma(c2(0.3275911f), a, c2(1.0f));
    f32x2 t;
    t.x = __builtin_amdgcn_rcpf(d.x);
    t.y = __builtin_amdgcn_rcpf(d.y);
    const f32x2 s = u * 1.20112240878645f;      // sqrt(log2 e)
    f32x2 e;
    e.x = __builtin_amdgcn_exp2f(-(s.x * s.x)); // exp(-u^2)
    e.y = __builtin_amdgcn_exp2f(-(s.y * s.y));
    f32x2 p = c2(1.061405429f);
    p = __builtin_elementwise_fma(p, t, c2(-1.453152027f));
    p = __builtin_elementwise_fma(p, t, c2( 1.421413741f));
    p = __builtin_elementwise_fma(p, t, c2(-0.284496736f));
    p = __builtin_elementwise_fma(p, t, c2( 0.254829592f));
    p = p * t;
    f32x2 er = __builtin_elementwise_fma(-p, e, c2(1.0f));
    er = __builtin_elementwise_copysign(er, u);
    const f32x2 zh = z * 0.5f;
    return __builtin_elementwise_fma(zh, er, zh);
}

__device__ __forceinline__ ushort bf16_hi(float f) {
    return (ushort)(__float_as_uint(f) >> 16);
}
__device__ __forceinline__ float bf16_f(ushort u) {
    return __uint_as_float(((unsigned)u) << 16);
}

// Pack top halves of two f32 bit-patterns into one u32: {lo16=a>>16, hi16=b>>16}.
#define PKHI(b_, a_) __builtin_amdgcn_perm((b_), (a_), 0x07060302u)

// One step, swapped form: D'[c'][r] = sum_k W^T[c'][k] h[k][r].
// A = W^T (static regs), B = h from swizzled LDS stripes (4x ds_read_b128).
// Bias rides as C-in of the ac1 chain at literal elements E0,E1.
// Elements E0,E1 finished with PACKED f32 math; one u32 write per plane.
#define STEP(RA0, RA1, WHI, WLO, XB, E0, E1) { \
    const bf16x8 Hhi0 = *reinterpret_cast<const bf16x8*>(RA0); \
    const bf16x8 Hlo0 = *reinterpret_cast<const bf16x8*>((RA0) + 64); \
    const bf16x8 Hhi1 = *reinterpret_cast<const bf16x8*>(RA1); \
    const bf16x8 Hlo1 = *reinterpret_cast<const bf16x8*>((RA1) + 64); \
    const f32x2 biv = __builtin_elementwise_fma(c2(XB), winv, cbv); \
    f32x4 ci = {0.f, 0.f, 0.f, 0.f}; \
    ci[E0] = biv.x; \
    ci[E1] = biv.y; \
    const f32x4 zz = {0.f, 0.f, 0.f, 0.f}; \
    f32x4 ahh = __builtin_amdgcn_mfma_f32_16x16x32_bf16(Whi0, Hhi0, zz, 0, 0, 0); \
    f32x4 ac1 = __builtin_amdgcn_mfma_f32_16x16x32_bf16(Whi0, Hlo0, ci, 0, 0, 0); \
    f32x4 ac2 = __builtin_amdgcn_mfma_f32_16x16x32_bf16(Wlo0, Hhi0, zz, 0, 0, 0); \
    ahh = __builtin_amdgcn_mfma_f32_16x16x32_bf16(Whi1, Hhi1, ahh, 0, 0, 0); \
    ac1 = __builtin_amdgcn_mfma_f32_16x16x32_bf16(Whi1, Hlo1, ac1, 0, 0, 0); \
    ac2 = __builtin_amdgcn_mfma_f32_16x16x32_bf16(Wlo1, Hhi1, ac2, 0, 0, 0); \
    f32x2 pa, pb, pc; \
    pa.x = ahh[E0]; pa.y = ahh[E1]; \
    pb.x = ac1[E0]; pb.y = ac1[E1]; \
    pc.x = ac2[E0]; pc.y = ac2[E1]; \
    const f32x2 zv = (pa + pb) + pc; \
    const f32x2 hv = fast_gelu2(zv); \
    const unsigned hb0 = __float_as_uint(hv.x), hb1 = __float_as_uint(hv.y); \
    *(WHI) = PKHI(hb1, hb0); \
    const f32x2 htr = { __uint_as_float(hb0 & 0xffff0000u), \
                        __uint_as_float(hb1 & 0xffff0000u) }; \
    const f32x2 lv = hv - htr; \
    *(WLO) = PKHI(__float_as_uint(lv.y), __float_as_uint(lv.x)); \
    __syncthreads(); }

// Main loop specialized per element-half so all C-vector indices are literals.
#define MAINLOOP(E0, E1) { \
    f32x2 winv, cbv; \
    winv.x = W_in[cq + E0]; winv.y = W_in[cq + E1]; \
    cbv.x  = b_in[cq + E0] + b_s[cq + E0]; \
    cbv.y  = b_in[cq + E1] + b_s[cq + E1]; \
    for (int tc = 0; tc < nch; ++tc) { \
        /* Re-pin W-frags each chunk: keeps them in arch VGPRs with a dense */ \
        /* live range. */ \
        asm volatile("" : "+v"(Whi0), "+v"(Whi1), "+v"(Wlo0), "+v"(Wlo1)); \
        const size_t tg = (size_t)tc * 64; \
        { \
            const int row = tid >> 5;        /* 0..15 */ \
            const int ch  = tid & 31;        /* 0..31 -> 2 floats each */ \
            const float2 xg = *reinterpret_cast<const float2*>( \
                &x[(size_t)(bA + row) * (size_t)T + tg + ch * 2]); \
            *reinterpret_cast<float2*>(&xlds[row][ch * 2]) = xg; \
        } \
        __syncthreads(); \
        _Pragma("unroll 1") \
        for (int t4 = 0; t4 < 16; ++t4) { \
            const f32x4 xq = *reinterpret_cast<const f32x4*>(&xlds[rr][t4 * 4]); \
            STEP(rA0, rA1, whiB, wloB, xq[0], E0, E1) \
            STEP(rB0, rB1, whiA, wloA, xq[1], E0, E1) \
            STEP(rA0, rA1, whiB, wloB, xq[2], E0, E1) \
            STEP(rB0, rB1, whiA, wloA, xq[3], E0, E1) \
        } \
    } }

__global__ __launch_bounds__(512, 2)
void ssm_kernel(const float* __restrict__ x,
                const float* __restrict__ W_in,
                const float* __restrict__ b_in,
                const float* __restrict__ W_s,
                const float* __restrict__ b_s,
                const float* __restrict__ W_out,
                const float* __restrict__ b_out,
                float* __restrict__ out,
                int B, int T) {
    // h state: per row one 288B stripe = [hi 8 slots][lo 8 slots][pad], XOR-swizzled
    // 16B slots (phys = s ^ (rr&7) ^ 5*(rr>>3)); ping-pong buffers.
    __shared__ ushort hlds[2][RPG * ROWU];
    __shared__ float  xlds[RPG][XSTR];      // x[row][t_local], padded

    const int tid  = threadIdx.x;
    const int ww   = tid >> 6;        // wave 0..7
    const int g    = ww & 3;          // c-tile: owns cols [16g, 16g+16)
    const int hf   = ww >> 2;         // element-half: finishes {2hf, 2hf+1}
    const int lane = tid & 63;
    const int q    = lane >> 4;
    const int rr   = lane & 15;       // lane's batch row (C col-index)
    const int bA   = blockIdx.x * RPG;
    const int cq   = 16 * g + 4 * q;  // c-quad base this lane produces

    if (bA >= B) return;

    // A-operand = W^T tile g (static): lane rr holds W^T[c'=rr][k=8q+e].
    bf16x8 Whi0, Whi1, Wlo0, Wlo1;
    const int wcol = 16 * g + rr;
#pragma unroll
    for (int e = 0; e < 8; ++e) {
        {   const float wf = W_s[(8 * q + e) * HID + wcol];
            const ushort hi = bf16_hi(wf);
            Whi0[e] = (short)hi;
            Wlo0[e] = (short)bf16_hi(wf - bf16_f(hi)); }
        {   const float wf = W_s[(32 + 8 * q + e) * HID + wcol];
            const ushort hi = bf16_hi(wf);
            Whi1[e] = (short)hi;
            Wlo1[e] = (short)bf16_hi(wf - bf16_f(hi)); }
    }
    asm volatile("" : "+v"(Whi0), "+v"(Whi1), "+v"(Wlo0), "+v"(Wlo1));

    // zero h buffers; ordered before first read by the staging barrier
    {
        ushort* p = &hlds[0][0];
        for (int i = tid; i < 2 * RPG * ROWU; i += 512) p[i] = 0;
    }

    // Swizzle for this lane's row.
    const int sx = (rr & 7) ^ ((rr >> 3) * 5);

    // Read addr regs: hi slot q and hi slot q^4 (lo at +64 ushorts = offset:128).
    const ushort* const rA0 = &hlds[0][rr * ROWU + 8 * (q ^ sx)];
    const ushort* const rA1 = &hlds[0][rr * ROWU + 8 * ((q ^ 4) ^ sx)];
    const ushort* const rB0 = &hlds[1][rr * ROWU + 8 * (q ^ sx)];
    const ushort* const rB1 = &hlds[1][rr * ROWU + 8 * ((q ^ 4) ^ sx)];

    // Write pointers: c0 = cq + 2hf -> logical slot l = c0>>3, within = c0&7.
    const int c0  = cq + 2 * hf;
    const int wl  = c0 >> 3;
    const int win_idx = rr * ROWU + 8 * (wl ^ sx) + (c0 & 7);
    unsigned* const whiA = reinterpret_cast<unsigned*>(&hlds[0][win_idx]);
    unsigned* const wloA = reinterpret_cast<unsigned*>(&hlds[0][win_idx + 64]);
    unsigned* const whiB = reinterpret_cast<unsigned*>(&hlds[1][win_idx]);
    unsigned* const wloB = reinterpret_cast<unsigned*>(&hlds[1][win_idx + 64]);

    const int nch = T >> 6;           // T multiple of 64 (8192 here)

    if (hf == 0) { MAINLOOP(0, 1) } else { MAINLOOP(2, 3) }

    // Epilogue: h final in hlds[0] (even step count). out[b] = h.W_out + b_out.
    if (ww == 0) {
        const int r  = lane >> 2;
        const int p4 = lane & 3;
        const int sxr = (r & 7) ^ ((r >> 3) * 5);
        float s = 0.f;
#pragma unroll
        for (int half = 0; half < 2; ++half) {
            const int slot = 2 * p4 + half;                 // logical slot
            const ushort* hp = &hlds[0][r * ROWU + 8 * (slot ^ sxr)];
            const ushort* lp = hp + 64;
#pragma unroll
            for (int j = 0; j < 8; ++j) {
                const float hv = bf16_f(hp[j]) + bf16_f(lp[j]);
                s = __builtin_fmaf(hv, W_out[8 * slot + j], s);
            }
        }
        s += __shfl_xor(s, 1, 64);
        s += __shfl_xor(s, 2, 64);
        if (p4 == 0) out[bA + r] = s + b_out[0];
    }
}

extern "C" void kernel_launch(void* const* d_in, const int* in_sizes, int n_in,
                              void* d_out, int out_size, void* d_ws, size_t ws_size,
                              hipStream_t stream) {
    const float* x     = (const float*)d_in[0];
    const float* W_in  = (const float*)d_in[1];
    const float* b_in  = (const float*)d_in[2];
    const float* W_s   = (const float*)d_in[3];
    const float* b_s   = (const float*)d_in[4];
    const float* W_out = (const float*)d_in[5];
    const float* b_out = (const float*)d_in[6];
    float* out = (float*)d_out;

    const int B = out_size;                 // [B,1] output
    const int T = in_sizes[0] / B;          // x is [B,T,1]

    const int blocks = B / RPG;             // 256 for B=4096
    ssm_kernel<<<blocks, 512, 0, stream>>>(
        x, W_in, b_in, W_s, b_s, W_out, b_out, out, B, T);
}